// Round 3
// baseline (113.382 us; speedup 1.0000x reference)
//
#include <hip/hip_runtime.h>
#include <stdint.h>

#define PNUM 128
#define BATCH 8192
#define WPB 4                      // waves per block, 1 batch per wave
#define GRID1 (BATCH / WPB)        // 2048 blocks of 256 threads

typedef uint32_t u32;
typedef uint32_t u32x2 __attribute__((ext_vector_type(2)));
typedef uint32_t u32x4 __attribute__((ext_vector_type(4)));

// f32x2 -> f16x2 (RTZ) packed into one u32
__device__ __forceinline__ u32 cvt2u(float x, float y) {
    return __builtin_bit_cast(u32, __builtin_amdgcn_cvt_pkrtz(x, y));
}

// One packed smooth-L1 term over both coords of a point pair, f32-accumulated.
// 5 packed instructions (R7-verified exact): d=p-q, a=|d|, m=min(a,1),
// t=a-0.5m, acc=dot2(m,t)+acc.
__device__ __forceinline__ void unit(u32 p, u32 q, float& acc, u32 cOne, u32 cNegHalf) {
    u32 d, a, m, t;
    asm("v_pk_add_f16 %0, %1, %2 neg_lo:[0,1] neg_hi:[0,1]" : "=v"(d) : "v"(p), "v"(q));
    asm("v_and_b32 %0, 0x7fff7fff, %1" : "=v"(a) : "v"(d));
    asm("v_pk_min_f16 %0, %1, %2" : "=v"(m) : "v"(a), "v"(cOne));
    asm("v_pk_fma_f16 %0, %1, %2, %3" : "=v"(t) : "v"(m), "v"(cNegHalf), "v"(a));
    asm("v_dot2_f32_f16 %0, %1, %2, %0" : "+v"(acc) : "v"(m), "v"(t));
}

// Pinned-register LDS loads the allocator cannot sink (R5/R6/R7: VGPR=20-24
// proved the compiler serializes ds_read->use; real DS latency ~120cyc).
#define DSR64(dst, addr, OFF) \
    asm volatile("ds_read_b64 %0, %1 offset:" OFF : "=v"(dst) : "v"(addr))
#define DSR128(dst, addr, OFF) \
    asm volatile("ds_read_b128 %0, %1 offset:" OFF : "=v"(dst) : "v"(addr))
// Counted wait + sched fence (guide rule #18: hipcc hoists reg-only asm past
// a bare lgkmcnt; sched_barrier(0) right after the wait is the required fence)
#define WAITLG(N) \
    asm volatile("s_waitcnt lgkmcnt(" #N ")" ::: "memory"); \
    __builtin_amdgcn_sched_barrier(0)

// 16 units of iteration i: buffer regs (naC,nbC = ring gathers; q0C,q1C =
// pred broadcasts), W = nb of iteration i-1 (lives in the previous buffer).
#define COMPUTE(naC, nbC, q0C, q1C, Wv) \
    unit(q0C[0], Wv[0],  a00, cOne, cNegHalf); \
    unit(q0C[1], Wv[1],  a00, cOne, cNegHalf); \
    unit(q0C[2], naC[0], a00, cOne, cNegHalf); \
    unit(q0C[3], naC[1], a00, cOne, cNegHalf); \
    unit(q0C[0], Wv[1],  a01, cOne, cNegHalf); \
    unit(q0C[1], naC[0], a01, cOne, cNegHalf); \
    unit(q0C[2], naC[1], a01, cOne, cNegHalf); \
    unit(q0C[3], nbC[0], a01, cOne, cNegHalf); \
    unit(q1C[0], Wv[0],  a10, cOne, cNegHalf); \
    unit(q1C[1], Wv[1],  a10, cOne, cNegHalf); \
    unit(q1C[2], naC[0], a10, cOne, cNegHalf); \
    unit(q1C[3], naC[1], a10, cOne, cNegHalf); \
    unit(q1C[0], Wv[1],  a11, cOne, cNegHalf); \
    unit(q1C[1], naC[0], a11, cOne, cNegHalf); \
    unit(q1C[2], naC[1], a11, cOne, cNegHalf); \
    unit(q1C[3], nbC[0], a11, cOne, cNegHalf)

// One WAVE per batch, both preds. Lane k owns shifts {2k,2k+1}.
// gt ring (doubled, f16) + pred rows in per-wave LDS.
// R8: triple-buffered asm DS pipeline — iterations i,i+1 in flight while
// computing i-1; steady-state s_waitcnt lgkmcnt(4); DS returns in-order so
// the counted wait lands exactly on this iteration's 4 loads. W(i)=nb(i-1)
// falls out of the buffer rotation (no copies). All offsets immediate;
// gA/pA advance +48B per 3-iter body; loop body ~260 instrs (icache-small).
__global__ __launch_bounds__(64 * WPB, 8) void match_fused(
        const float* __restrict__ pred0,
        const float* __restrict__ pred1,
        const float* __restrict__ gt,
        float* __restrict__ out) {
    __shared__ __align__(16) _Float16 lds[WPB][1024];  // ring 1024B | q0 512B | q1 512B
    __shared__ float bsum[WPB];

    const int t = threadIdx.x;
    const int k = t & 63;
    const int w = __builtin_amdgcn_readfirstlane(t >> 6);
    const int b = blockIdx.x * WPB + w;

    _Float16* base = lds[w];
    uint2* ringU = (uint2*)base;              // 128 entries (doubled ring)
    uint2* q0s   = (uint2*)(base + 512);      // f16-idx 512 = byte 1024
    uint2* q1s   = (uint2*)(base + 768);      // byte 1536

    // ---- stage + f32->f16 convert (own wave's region; no barrier needed) ----
    const float4* gv4 = (const float4*)(gt    + (size_t)b * (PNUM * 2));
    const float4* p0v = (const float4*)(pred0 + (size_t)b * (PNUM * 2));
    const float4* p1v = (const float4*)(pred1 + (size_t)b * (PNUM * 2));
    {
        float4 g = gv4[k];
        uint2 gh = {cvt2u(g.x, g.y), cvt2u(g.z, g.w)};
        ringU[k] = gh; ringU[k + 64] = gh;
        float4 p = p0v[k];
        q0s[k] = (uint2){cvt2u(p.x, p.y), cvt2u(p.z, p.w)};
        p = p1v[k];
        q1s[k] = (uint2){cvt2u(p.x, p.y), cvt2u(p.z, p.w)};
    }

    // raw LDS byte addresses for asm DS ops
    u32 ldsb = (u32)(uintptr_t)base;
    u32 gA = ldsb + (u32)(k * 8);     // gather base (lane-sliding)
    u32 pA = ldsb + 1024;             // pred broadcast base (wave-uniform)

    // staging writes must land before asm reads (same-wave DS is in-order,
    // but make it explicit and fence the scheduler)
    asm volatile("s_waitcnt lgkmcnt(0)" ::: "memory");
    __builtin_amdgcn_sched_barrier(0);

    u32 cOne = 0x3C003C00u;      // packed f16 {1.0, 1.0}
    u32 cNegHalf = 0xB800B800u;  // packed f16 {-0.5, -0.5}

    u32x2 na0, nb0, na1, nb1, na2, nb2;
    u32x4 q0b0, q1b0, q0b1, q1b1, q0b2, q1b2;

    // ---- prologue: W(iter0)=ring[k] into nb2; issue L0 (buf0), L1 (buf1) ----
    DSR64(nb2, gA, "0");
    DSR64(na0, gA, "8");   DSR64(nb0, gA, "16");
    DSR128(q0b0, pA, "0"); DSR128(q1b0, pA, "512");
    DSR64(na1, gA, "24");  DSR64(nb1, gA, "32");
    DSR128(q0b1, pA, "16"); DSR128(q1b1, pA, "528");

    float a00 = 0.f, a01 = 0.f, a10 = 0.f, a11 = 0.f;

    for (int bdy = 0; bdy < 10; ++bdy) {   // iters 3b, 3b+1, 3b+2 (0..29)
        // sub0: iter 3b (buf0, W=nb2); issue L_{3b+2} -> buf2
        WAITLG(4);
        COMPUTE(na0, nb0, q0b0, q1b0, nb2);
        DSR64(na2, gA, "40");  DSR64(nb2, gA, "48");
        DSR128(q0b2, pA, "32"); DSR128(q1b2, pA, "544");
        // sub1: iter 3b+1 (buf1, W=nb0); issue L_{3b+3} -> buf0
        WAITLG(4);
        COMPUTE(na1, nb1, q0b1, q1b1, nb0);
        DSR64(na0, gA, "56");  DSR64(nb0, gA, "64");
        DSR128(q0b0, pA, "48"); DSR128(q1b0, pA, "560");
        // sub2: iter 3b+2 (buf2, W=nb1); issue L_{3b+4} -> buf1
        WAITLG(4);
        COMPUTE(na2, nb2, q0b2, q1b2, nb1);
        DSR64(na1, gA, "72");  DSR64(nb1, gA, "80");
        DSR128(q0b1, pA, "64"); DSR128(q1b1, pA, "576");
        gA += 48; pA += 48;
    }
    // ---- epilogue: iters 30 (buf0, W=nb2) and 31 (buf1, W=nb0) ----
    WAITLG(4);
    COMPUTE(na0, nb0, q0b0, q1b0, nb2);
    WAITLG(0);
    COMPUTE(na1, nb1, q0b1, q1b1, nb0);

    // per-pred min over lane's 2 shifts, then over the wave
    float r0 = fminf(a00, a01);
    float r1 = fminf(a10, a11);
#pragma unroll
    for (int m = 32; m > 0; m >>= 1) {
        r0 = fminf(r0, __shfl_xor(r0, m, 64));
        r1 = fminf(r1, __shfl_xor(r1, m, 64));
    }

    if (k == 0) bsum[w] = r0 + r1;
    __syncthreads();
    if (t == 0) {
        float blockpart = bsum[0] + bsum[1] + bsum[2] + bsum[3];
        // relaxed device-scope atomic; NO fence (R5 lesson: fences -> L2 writeback storm)
        atomicAdd(out, blockpart * (1.0f / (2.0f * BATCH * PNUM)));
    }
}

extern "C" void kernel_launch(void* const* d_in, const int* in_sizes, int n_in,
                              void* d_out, int out_size, void* d_ws, size_t ws_size,
                              hipStream_t stream) {
    const float* pred0 = (const float*)d_in[0];
    const float* pred1 = (const float*)d_in[1];
    const float* gt    = (const float*)d_in[2];
    float* out = (float*)d_out;

    (void)hipMemsetAsync(out, 0, sizeof(float), stream);   // out is 0xAA-poisoned
    match_fused<<<GRID1, 64 * WPB, 0, stream>>>(pred0, pred1, gt, out);
}

// Round 4
// 111.636 us; speedup vs baseline: 1.0156x; 1.0156x over previous
//
#include <hip/hip_runtime.h>
#include <stdint.h>

#define PNUM 128
#define BATCH 8192
#define WPB 4                      // waves per block, 1 batch per wave
#define GRID1 (BATCH / WPB)        // 2048 blocks of 256 threads

typedef uint32_t u32;
typedef uint32_t u32x2 __attribute__((ext_vector_type(2)));
typedef uint32_t u32x4 __attribute__((ext_vector_type(4)));

// f32x2 -> f16x2 (RTZ) packed into one u32
__device__ __forceinline__ u32 cvt2u(float x, float y) {
    return __builtin_bit_cast(u32, __builtin_amdgcn_cvt_pkrtz(x, y));
}

// One packed smooth-L1 term over both coords of a point pair, f32-accumulated.
// 5 packed instructions (R7-verified exact): d=p-q, a=|d|, m=min(a,1),
// t=a-0.5m, acc=dot2(m,t)+acc.
__device__ __forceinline__ void unit(u32 p, u32 q, float& acc, u32 cOne, u32 cNegHalf) {
    u32 d, a, m, t;
    asm("v_pk_add_f16 %0, %1, %2 neg_lo:[0,1] neg_hi:[0,1]" : "=v"(d) : "v"(p), "v"(q));
    asm("v_and_b32 %0, 0x7fff7fff, %1" : "=v"(a) : "v"(d));
    asm("v_pk_min_f16 %0, %1, %2" : "=v"(m) : "v"(a), "v"(cOne));
    asm("v_pk_fma_f16 %0, %1, %2, %3" : "=v"(t) : "v"(m), "v"(cNegHalf), "v"(a));
    asm("v_dot2_f32_f16 %0, %1, %2, %0" : "+v"(acc) : "v"(m), "v"(t));
}

#define DSR64(dst, addr, OFF) \
    asm volatile("ds_read_b64 %0, %1 offset:" OFF : "=v"(dst) : "v"(addr))
#define DSR128(dst, addr, OFF) \
    asm volatile("ds_read_b128 %0, %1 offset:" OFF : "=v"(dst) : "v"(addr))
#define WAITLG(N) \
    asm volatile("s_waitcnt lgkmcnt(" #N ")" ::: "memory"); \
    __builtin_amdgcn_sched_barrier(0)

#define COMPUTE(naC, nbC, q0C, q1C, Wv) \
    unit(q0C[0], Wv[0],  a00, cOne, cNegHalf); \
    unit(q0C[1], Wv[1],  a00, cOne, cNegHalf); \
    unit(q0C[2], naC[0], a00, cOne, cNegHalf); \
    unit(q0C[3], naC[1], a00, cOne, cNegHalf); \
    unit(q0C[0], Wv[1],  a01, cOne, cNegHalf); \
    unit(q0C[1], naC[0], a01, cOne, cNegHalf); \
    unit(q0C[2], naC[1], a01, cOne, cNegHalf); \
    unit(q0C[3], nbC[0], a01, cOne, cNegHalf); \
    unit(q1C[0], Wv[0],  a10, cOne, cNegHalf); \
    unit(q1C[1], Wv[1],  a10, cOne, cNegHalf); \
    unit(q1C[2], naC[0], a10, cOne, cNegHalf); \
    unit(q1C[3], naC[1], a10, cOne, cNegHalf); \
    unit(q1C[0], Wv[1],  a11, cOne, cNegHalf); \
    unit(q1C[1], naC[0], a11, cOne, cNegHalf); \
    unit(q1C[2], naC[1], a11, cOne, cNegHalf); \
    unit(q1C[3], nbC[0], a11, cOne, cNegHalf)

// R9: IDENTICAL compute to R8 (triple-buffered asm DS pipeline). The ONLY
// change: no same-address atomicAdd. R5-R8 evidence: three structurally
// different compute kernels all land at 48-50us => duration not set by
// compute. 2048 device-scope atomics to ONE line across 8 XCDs at ~60cyc
// serialized RMW = ~51us ~= the measured 49us. Kernel now plain-stores one
// partial per block to d_ws (2048 distinct addresses, no serialization);
// a tiny second kernel reduces them.
__global__ __launch_bounds__(64 * WPB, 8) void match_fused(
        const float* __restrict__ pred0,
        const float* __restrict__ pred1,
        const float* __restrict__ gt,
        float* __restrict__ ws) {
    __shared__ __align__(16) _Float16 lds[WPB][1024];  // ring 1024B | q0 512B | q1 512B
    __shared__ float bsum[WPB];

    const int t = threadIdx.x;
    const int k = t & 63;
    const int w = __builtin_amdgcn_readfirstlane(t >> 6);
    const int b = blockIdx.x * WPB + w;

    _Float16* base = lds[w];
    uint2* ringU = (uint2*)base;              // 128 entries (doubled ring)
    uint2* q0s   = (uint2*)(base + 512);      // byte 1024
    uint2* q1s   = (uint2*)(base + 768);      // byte 1536

    // ---- stage + f32->f16 convert (own wave's region; no barrier needed) ----
    const float4* gv4 = (const float4*)(gt    + (size_t)b * (PNUM * 2));
    const float4* p0v = (const float4*)(pred0 + (size_t)b * (PNUM * 2));
    const float4* p1v = (const float4*)(pred1 + (size_t)b * (PNUM * 2));
    {
        float4 g = gv4[k];
        uint2 gh = {cvt2u(g.x, g.y), cvt2u(g.z, g.w)};
        ringU[k] = gh; ringU[k + 64] = gh;
        float4 p = p0v[k];
        q0s[k] = (uint2){cvt2u(p.x, p.y), cvt2u(p.z, p.w)};
        p = p1v[k];
        q1s[k] = (uint2){cvt2u(p.x, p.y), cvt2u(p.z, p.w)};
    }

    // raw LDS byte addresses for asm DS ops
    u32 ldsb = (u32)(uintptr_t)base;
    u32 gA = ldsb + (u32)(k * 8);     // gather base (lane-sliding)
    u32 pA = ldsb + 1024;             // pred broadcast base (wave-uniform)

    asm volatile("s_waitcnt lgkmcnt(0)" ::: "memory");
    __builtin_amdgcn_sched_barrier(0);

    u32 cOne = 0x3C003C00u;      // packed f16 {1.0, 1.0}
    u32 cNegHalf = 0xB800B800u;  // packed f16 {-0.5, -0.5}

    u32x2 na0, nb0, na1, nb1, na2, nb2;
    u32x4 q0b0, q1b0, q0b1, q1b1, q0b2, q1b2;

    // ---- prologue: W(iter0)=ring[k] into nb2; issue L0 (buf0), L1 (buf1) ----
    DSR64(nb2, gA, "0");
    DSR64(na0, gA, "8");   DSR64(nb0, gA, "16");
    DSR128(q0b0, pA, "0"); DSR128(q1b0, pA, "512");
    DSR64(na1, gA, "24");  DSR64(nb1, gA, "32");
    DSR128(q0b1, pA, "16"); DSR128(q1b1, pA, "528");

    float a00 = 0.f, a01 = 0.f, a10 = 0.f, a11 = 0.f;

    for (int bdy = 0; bdy < 10; ++bdy) {   // iters 3b, 3b+1, 3b+2 (0..29)
        WAITLG(4);
        COMPUTE(na0, nb0, q0b0, q1b0, nb2);
        DSR64(na2, gA, "40");  DSR64(nb2, gA, "48");
        DSR128(q0b2, pA, "32"); DSR128(q1b2, pA, "544");
        WAITLG(4);
        COMPUTE(na1, nb1, q0b1, q1b1, nb0);
        DSR64(na0, gA, "56");  DSR64(nb0, gA, "64");
        DSR128(q0b0, pA, "48"); DSR128(q1b0, pA, "560");
        WAITLG(4);
        COMPUTE(na2, nb2, q0b2, q1b2, nb1);
        DSR64(na1, gA, "72");  DSR64(nb1, gA, "80");
        DSR128(q0b1, pA, "64"); DSR128(q1b1, pA, "576");
        gA += 48; pA += 48;
    }
    // ---- epilogue: iters 30 (buf0, W=nb2) and 31 (buf1, W=nb0) ----
    WAITLG(4);
    COMPUTE(na0, nb0, q0b0, q1b0, nb2);
    WAITLG(0);
    COMPUTE(na1, nb1, q0b1, q1b1, nb0);

    // per-pred min over lane's 2 shifts, then over the wave
    float r0 = fminf(a00, a01);
    float r1 = fminf(a10, a11);
#pragma unroll
    for (int m = 32; m > 0; m >>= 1) {
        r0 = fminf(r0, __shfl_xor(r0, m, 64));
        r1 = fminf(r1, __shfl_xor(r1, m, 64));
    }

    if (k == 0) bsum[w] = r0 + r1;
    __syncthreads();
    if (t == 0) {
        // plain store, 2048 distinct addresses -> no cross-XCD RMW chain
        ws[blockIdx.x] = bsum[0] + bsum[1] + bsum[2] + bsum[3];
    }
}

// Second dispatch: sum 2048 per-block partials, scale, write out.
__global__ __launch_bounds__(256) void reduce_out(
        const float* __restrict__ ws, float* __restrict__ out) {
    const int t = threadIdx.x;
    const float4* w4 = (const float4*)ws;
    float4 v0 = w4[t];           // 256 * 4 = 1024 partials
    float4 v1 = w4[t + 256];     // + 1024 = 2048
    float s = ((v0.x + v0.y) + (v0.z + v0.w)) + ((v1.x + v1.y) + (v1.z + v1.w));
#pragma unroll
    for (int m = 32; m > 0; m >>= 1) s += __shfl_xor(s, m, 64);
    __shared__ float acc[4];
    const int w = t >> 6;
    if ((t & 63) == 0) acc[w] = s;
    __syncthreads();
    if (t == 0)
        out[0] = (acc[0] + acc[1] + acc[2] + acc[3]) * (1.0f / (2.0f * BATCH * PNUM));
}

extern "C" void kernel_launch(void* const* d_in, const int* in_sizes, int n_in,
                              void* d_out, int out_size, void* d_ws, size_t ws_size,
                              hipStream_t stream) {
    const float* pred0 = (const float*)d_in[0];
    const float* pred1 = (const float*)d_in[1];
    const float* gt    = (const float*)d_in[2];
    float* out = (float*)d_out;
    float* ws  = (float*)d_ws;      // 2048 floats = 8 KB of workspace

    match_fused<<<GRID1, 64 * WPB, 0, stream>>>(pred0, pred1, gt, ws);
    reduce_out<<<1, 256, 0, stream>>>(ws, out);
}